// Round 5
// baseline (456.579 us; speedup 1.0000x reference)
//
#include <hip/hip_runtime.h>
#include <math.h>

__device__ __forceinline__ int f2oi(float f) {
    int i = __float_as_int(f);
    return i >= 0 ? i : (i ^ 0x7FFFFFFF);
}
__device__ __forceinline__ float oi2f(int i) {
    return __int_as_float(i >= 0 ? i : (i ^ 0x7FFFFFFF));
}

// ---------- GEMM + fused attention logits ----------
template<int M, int NJ, int H>
__global__ __launch_bounds__(256) void gemm_logits(const float* __restrict__ X,
                                                   const float* __restrict__ W,
                                                   const float* __restrict__ a_src,
                                                   const float* __restrict__ a_dst,
                                                   float* __restrict__ Hout,
                                                   float* __restrict__ als,
                                                   float* __restrict__ ald, int N) {
    __shared__ float Wl[M * 128];
    for (int i = threadIdx.x; i < M * 32; i += 256) {
        int j = i >> 5, kg = i & 31;
        float4 w = reinterpret_cast<const float4*>(W)[i];
        int ks = (kg * 4) ^ ((j & 7) << 2);
        *reinterpret_cast<float4*>(&Wl[j * 128 + ks]) = w;
    }
    __syncthreads();

    int lane16 = threadIdx.x & 15;
    int rb = threadIdx.x >> 4;
    int base = blockIdx.x * 64;

    const float4* xr[4];
    int rows[4];
#pragma unroll
    for (int q = 0; q < 4; q++) {
        int row = base + rb + q * 16;
        rows[q] = row;
        int rc = row < N ? row : 0;
        xr[q] = reinterpret_cast<const float4*>(X + (long long)rc * 128);
    }

    float acc[4][NJ];
#pragma unroll
    for (int q = 0; q < 4; q++)
#pragma unroll
        for (int jj = 0; jj < NJ; jj++) acc[q][jj] = 0.f;

#pragma unroll 4
    for (int kg = 0; kg < 32; kg++) {
        float4 xv0 = xr[0][kg];
        float4 xv1 = xr[1][kg];
        float4 xv2 = xr[2][kg];
        float4 xv3 = xr[3][kg];
#pragma unroll
        for (int jj = 0; jj < NJ; jj++) {
            int j = lane16 + jj * 16;
            if (M == 128 || j < M) {
                const float4 wv = *reinterpret_cast<const float4*>(
                    &Wl[j * 128 + ((kg * 4) ^ ((j & 7) << 2))]);
                acc[0][jj] = fmaf(xv0.x, wv.x, fmaf(xv0.y, wv.y, fmaf(xv0.z, wv.z, fmaf(xv0.w, wv.w, acc[0][jj]))));
                acc[1][jj] = fmaf(xv1.x, wv.x, fmaf(xv1.y, wv.y, fmaf(xv1.z, wv.z, fmaf(xv1.w, wv.w, acc[1][jj]))));
                acc[2][jj] = fmaf(xv2.x, wv.x, fmaf(xv2.y, wv.y, fmaf(xv2.z, wv.z, fmaf(xv2.w, wv.w, acc[2][jj]))));
                acc[3][jj] = fmaf(xv3.x, wv.x, fmaf(xv3.y, wv.y, fmaf(xv3.z, wv.z, fmaf(xv3.w, wv.w, acc[3][jj]))));
            }
        }
    }

    float asv[NJ], adv[NJ];
#pragma unroll
    for (int jj = 0; jj < NJ; jj++) {
        int j = lane16 + jj * 16;
        asv[jj] = (j < M) ? a_src[j] : 0.f;
        adv[jj] = (j < M) ? a_dst[j] : 0.f;
    }

#pragma unroll
    for (int q = 0; q < 4; q++) {
        int row = rows[q];
        float hs[H], hd[H];
#pragma unroll
        for (int h = 0; h < H; h++) { hs[h] = 0.f; hd[h] = 0.f; }
#pragma unroll
        for (int jj = 0; jj < NJ; jj++) {
            int h = (H == 1) ? 0 : (jj >> 1);
            hs[h] = fmaf(acc[q][jj], asv[jj], hs[h]);
            hd[h] = fmaf(acc[q][jj], adv[jj], hd[h]);
        }
#pragma unroll
        for (int off = 8; off >= 1; off >>= 1) {
#pragma unroll
            for (int h = 0; h < H; h++) {
                hs[h] += __shfl_xor(hs[h], off, 64);
                hd[h] += __shfl_xor(hd[h], off, 64);
            }
        }
        if (row < N) {
            if (lane16 < H) als[row * H + lane16] = hs[lane16];
            if (lane16 >= 8 && lane16 < 8 + H) ald[row * H + (lane16 - 8)] = hd[lane16 - 8];
#pragma unroll
            for (int jj = 0; jj < NJ; jj++) {
                int j = lane16 + jj * 16;
                if (j < M) Hout[(long long)row * M + j] = acc[q][jj];
            }
        }
    }
}

// ---------- global max of als/ald per head (softmax shift) ----------
// mint[0..H-1] = max als per head, mint[4..4+H-1] = max ald per head (ordered-int).
__global__ __launch_bounds__(256) void maxred(const float* __restrict__ als,
                                              const float* __restrict__ ald,
                                              int NH, int H, int* __restrict__ mint) {
    int gid = blockIdx.x * 256 + threadIdx.x;
    int T = gridDim.x * 256;
    int lane = threadIdx.x & 63;
    int h = lane & (H - 1);
    float ms = -INFINITY, md = -INFINITY;
    for (int i = gid; i < NH; i += T) {
        ms = fmaxf(ms, als[i]);
        md = fmaxf(md, ald[i]);
    }
    for (int off = H; off < 64; off <<= 1) {
        ms = fmaxf(ms, __shfl_xor(ms, off, 64));
        md = fmaxf(md, __shfl_xor(md, off, 64));
    }
    if (lane < H) {
        atomicMax(&mint[h], f2oi(ms));
        atomicMax(&mint[4 + h], f2oi(md));
    }
}

// ---------- CSR build ----------
__global__ void hist_dst(const int* __restrict__ dst, int E_real, int E_tot,
                         int* __restrict__ counts) {
    int e = blockIdx.x * blockDim.x + threadIdx.x;
    if (e >= E_tot) return;
    int d = (e < E_real) ? dst[e] : e - E_real;
    atomicAdd(&counts[d], 1);
}

__global__ __launch_bounds__(256) void scanA(const int* __restrict__ counts,
                                             int* __restrict__ offsets,
                                             int* __restrict__ blockTot, int N) {
    __shared__ int sh[256];
    int tid = threadIdx.x;
    int base = blockIdx.x * 1024 + tid * 4;
    int v0 = 0, v1 = 0, v2 = 0, v3 = 0;
    if (base + 0 < N) v0 = counts[base + 0];
    if (base + 1 < N) v1 = counts[base + 1];
    if (base + 2 < N) v2 = counts[base + 2];
    if (base + 3 < N) v3 = counts[base + 3];
    int s = v0 + v1 + v2 + v3;
    sh[tid] = s;
    __syncthreads();
    for (int off = 1; off < 256; off <<= 1) {
        int t = (tid >= off) ? sh[tid - off] : 0;
        __syncthreads();
        sh[tid] += t;
        __syncthreads();
    }
    int run = sh[tid] - s;
    if (base + 0 < N) { offsets[base + 0] = run; run += v0; }
    if (base + 1 < N) { offsets[base + 1] = run; run += v1; }
    if (base + 2 < N) { offsets[base + 2] = run; run += v2; }
    if (base + 3 < N) { offsets[base + 3] = run; }
    if (tid == 255) blockTot[blockIdx.x] = sh[255];
}

__global__ __launch_bounds__(256) void scanB(const int* __restrict__ blockTot,
                                             int* __restrict__ blockPre,
                                             int* __restrict__ offsets, int SB, int N) {
    __shared__ int sh[256];
    int tid = threadIdx.x;
    int v = (tid < SB) ? blockTot[tid] : 0;
    sh[tid] = v;
    __syncthreads();
    for (int off = 1; off < 256; off <<= 1) {
        int t = (tid >= off) ? sh[tid - off] : 0;
        __syncthreads();
        sh[tid] += t;
        __syncthreads();
    }
    blockPre[tid] = sh[tid] - v;
    if (tid == 255) offsets[N] = sh[255];
}

__global__ __launch_bounds__(256) void scanC(int* __restrict__ offsets,
                                             int* __restrict__ cursor,
                                             const int* __restrict__ blockPre, int N) {
    int pre = blockPre[blockIdx.x];
    int base = blockIdx.x * 1024 + threadIdx.x * 4;
#pragma unroll
    for (int j = 0; j < 4; j++) {
        int i = base + j;
        if (i < N) {
            int o = offsets[i] + pre;
            offsets[i] = o;
            cursor[i] = o;
        }
    }
}

__global__ void scatter_src(const int* __restrict__ src, const int* __restrict__ dst,
                            int E_real, int E_tot, int* __restrict__ cursor,
                            int* __restrict__ csr_src) {
    int e = blockIdx.x * blockDim.x + threadIdx.x;
    if (e >= E_tot) return;
    int s, d;
    if (e < E_real) { s = src[e]; d = dst[e]; } else { s = d = e - E_real; }
    int pos = atomicAdd(&cursor[d], 1);
    csr_src[pos] = s;
}

// ---------- fused GAT aggregate, layers 0/1 (H=4,C=32) ----------
// Per 64-edge chunk: lane e computes all 4 head weights once -> LDS; gather loop
// reads w,s via LDS broadcast. Global shift (mint) replaces per-node segment max.
__global__ __launch_bounds__(256) void gat_agg128(const int* __restrict__ offsets,
                                                  const int* __restrict__ csr_src,
                                                  const float* __restrict__ h,
                                                  const float* __restrict__ als,
                                                  const float* __restrict__ ald,
                                                  const int* __restrict__ mint,
                                                  const float* __restrict__ bias,
                                                  float* __restrict__ out, int N) {
    __shared__ float wlds[4][64][4];
    __shared__ int   slds[4][64];
    int wid = threadIdx.x >> 6;
    int lane = threadIdx.x & 63;
    int gwid = (blockIdx.x * 256 + threadIdx.x) >> 6;
    int nWaves = (gridDim.x * 256) >> 6;
    int hh = lane >> 4;
    const float2* h2 = (const float2*)h;
    const float4* als4 = (const float4*)als;
    const float4* ald4 = (const float4*)ald;
    float2 bv = ((const float2*)bias)[lane];

    float4 shift;
    {
        float v;
        v = oi2f(mint[0]) + oi2f(mint[4]); shift.x = v > 0.f ? v : 0.2f * v;
        v = oi2f(mint[1]) + oi2f(mint[5]); shift.y = v > 0.f ? v : 0.2f * v;
        v = oi2f(mint[2]) + oi2f(mint[6]); shift.z = v > 0.f ? v : 0.2f * v;
        v = oi2f(mint[3]) + oi2f(mint[7]); shift.w = v > 0.f ? v : 0.2f * v;
    }

    for (int n = gwid; n < N; n += nWaves) {
        int beg = offsets[n], end = offsets[n + 1];
        float4 adn = ald4[n];
        float accx = 0.f, accy = 0.f, den = 0.f;

        for (int c0 = beg; c0 < end; c0 += 64) {
            int e = c0 + lane;
            if (e < end) {
                int s = csr_src[e];
                float4 a4 = als4[s];
                float4 w; float v;
                v = a4.x + adn.x; v = v > 0.f ? v : 0.2f * v; w.x = __expf(v - shift.x);
                v = a4.y + adn.y; v = v > 0.f ? v : 0.2f * v; w.y = __expf(v - shift.y);
                v = a4.z + adn.z; v = v > 0.f ? v : 0.2f * v; w.z = __expf(v - shift.z);
                v = a4.w + adn.w; v = v > 0.f ? v : 0.2f * v; w.w = __expf(v - shift.w);
                *reinterpret_cast<float4*>(&wlds[wid][lane][0]) = w;
                slds[wid][lane] = s;
            }
            int cnt = end - c0; if (cnt > 64) cnt = 64;
            int p = 0;
            for (; p + 2 <= cnt; p += 2) {
                float w0 = wlds[wid][p][hh];     int s0 = slds[wid][p];
                float w1 = wlds[wid][p + 1][hh]; int s1 = slds[wid][p + 1];
                float2 hv0 = h2[(size_t)s0 * 64 + lane];
                float2 hv1 = h2[(size_t)s1 * 64 + lane];
                den += w0 + w1;
                accx = fmaf(hv0.x, w0, fmaf(hv1.x, w1, accx));
                accy = fmaf(hv0.y, w0, fmaf(hv1.y, w1, accy));
            }
            if (p < cnt) {
                float w0 = wlds[wid][p][hh]; int s0 = slds[wid][p];
                float2 hv0 = h2[(size_t)s0 * 64 + lane];
                den += w0;
                accx = fmaf(hv0.x, w0, accx);
                accy = fmaf(hv0.y, w0, accy);
            }
        }
        float inv = 1.f / den;
        float r0 = accx * inv + bv.x;
        float r1 = accy * inv + bv.y;
        float2 o;
        o.x = r0 > 0.f ? r0 : expm1f(r0);
        o.y = r1 > 0.f ? r1 : expm1f(r1);
        ((float2*)out)[(size_t)n * 64 + lane] = o;
    }
}

// ---------- fused GAT aggregate + log_softmax, layer 2 (H=1,C=40) ----------
__global__ __launch_bounds__(256) void gat_agg40_lsm(const int* __restrict__ offsets,
                                                     const int* __restrict__ csr_src,
                                                     const float* __restrict__ h,
                                                     const float* __restrict__ als,
                                                     const float* __restrict__ ald,
                                                     const int* __restrict__ mint,
                                                     const float* __restrict__ b2,
                                                     float* __restrict__ out, int N) {
    __shared__ float wlds[4][64];
    __shared__ int   slds[4][64];
    int wid = threadIdx.x >> 6;
    int lane = threadIdx.x & 63;
    int gwid = (blockIdx.x * 256 + threadIdx.x) >> 6;
    int nWaves = (gridDim.x * 256) >> 6;

    float shift;
    {
        float v = oi2f(mint[0]) + oi2f(mint[4]);
        shift = v > 0.f ? v : 0.2f * v;
    }

    for (int n = gwid; n < N; n += nWaves) {
        int beg = offsets[n], end = offsets[n + 1];
        float adn = ald[n];
        float acc = 0.f, den = 0.f;

        for (int c0 = beg; c0 < end; c0 += 64) {
            int e = c0 + lane;
            if (e < end) {
                int s = csr_src[e];
                float v = als[s] + adn; v = v > 0.f ? v : 0.2f * v;
                wlds[wid][lane] = __expf(v - shift);
                slds[wid][lane] = s;
            }
            int cnt = end - c0; if (cnt > 64) cnt = 64;
            int p = 0;
            for (; p + 2 <= cnt; p += 2) {
                float w0 = wlds[wid][p];     int s0 = slds[wid][p];
                float w1 = wlds[wid][p + 1]; int s1 = slds[wid][p + 1];
                float hv0 = (lane < 40) ? h[(size_t)s0 * 40 + lane] : 0.f;
                float hv1 = (lane < 40) ? h[(size_t)s1 * 40 + lane] : 0.f;
                den += w0 + w1;
                acc = fmaf(hv0, w0, fmaf(hv1, w1, acc));
            }
            if (p < cnt) {
                float w0 = wlds[wid][p]; int s0 = slds[wid][p];
                float hv0 = (lane < 40) ? h[(size_t)s0 * 40 + lane] : 0.f;
                den += w0;
                acc = fmaf(hv0, w0, acc);
            }
        }
        float val = (lane < 40) ? acc / den + b2[lane] : -INFINITY;
        float mx = val;
#pragma unroll
        for (int off = 32; off >= 1; off >>= 1) mx = fmaxf(mx, __shfl_xor(mx, off, 64));
        float pe = (lane < 40) ? __expf(val - mx) : 0.f;
        float sum = pe;
#pragma unroll
        for (int off = 32; off >= 1; off >>= 1) sum += __shfl_xor(sum, off, 64);
        if (lane < 40) out[n * 40 + lane] = val - mx - logf(sum);
    }
}

extern "C" void kernel_launch(void* const* d_in, const int* in_sizes, int n_in,
                              void* d_out, int out_size, void* d_ws, size_t ws_size,
                              hipStream_t stream) {
    const float* x      = (const float*)d_in[0];
    const int*   ei     = (const int*)d_in[1];
    const float* W0     = (const float*)d_in[2];
    const float* a_src0 = (const float*)d_in[3];
    const float* a_dst0 = (const float*)d_in[4];
    const float* b0     = (const float*)d_in[5];
    const float* W1     = (const float*)d_in[6];
    const float* a_src1 = (const float*)d_in[7];
    const float* a_dst1 = (const float*)d_in[8];
    const float* b1     = (const float*)d_in[9];
    const float* W2     = (const float*)d_in[10];
    const float* a_src2 = (const float*)d_in[11];
    const float* a_dst2 = (const float*)d_in[12];
    const float* b2     = (const float*)d_in[13];

    const int N = in_sizes[0] / 128;          // 50000
    const int E_real = in_sizes[1] / 2;       // 800000
    const int E_tot = E_real + N;
    const int* src = ei;
    const int* dst = ei + E_real;

    unsigned char* ws = (unsigned char*)d_ws;
    const size_t szH = (size_t)N * 128 * sizeof(float);
    float* bufH     = (float*)(ws);
    float* bufAcc   = (float*)(ws + szH);
    float* als      = (float*)(ws + 2 * szH);
    float* ald      = (float*)(ws + 2 * szH + (size_t)N * 4 * sizeof(float));
    int*   offsets  = (int*)  (ws + 2 * szH + (size_t)N * 8 * sizeof(float));
    int*   counts   = offsets + (N + 1);
    int*   cursor   = counts + N;
    int*   blockTot = cursor + N;
    int*   blockPre = blockTot + 256;
    int*   mint     = blockPre + 256;
    int*   csr_src  = mint + 8;               // E_tot ints

    const int B = 256;
    const int gRows64 = (N + 63) / 64;
    const int gEdge = (E_tot + B - 1) / B;
    const int SB    = (N + 1023) / 1024;
    const int gAgg  = 2048;

    // ===== CSR build (once) =====
    hipMemsetAsync(counts, 0, (size_t)N * sizeof(int), stream);
    hist_dst<<<gEdge, B, 0, stream>>>(dst, E_real, E_tot, counts);
    scanA<<<SB, B, 0, stream>>>(counts, offsets, blockTot, N);
    scanB<<<1, B, 0, stream>>>(blockTot, blockPre, offsets, SB, N);
    scanC<<<SB, B, 0, stream>>>(offsets, cursor, blockPre, N);
    scatter_src<<<gEdge, B, 0, stream>>>(src, dst, E_real, E_tot, cursor, csr_src);

    // ===== Layer 0 =====
    gemm_logits<128, 8, 4><<<gRows64, B, 0, stream>>>(x, W0, a_src0, a_dst0, bufH, als, ald, N);
    hipMemsetAsync(mint, 0x80, 8 * sizeof(int), stream);
    maxred<<<128, B, 0, stream>>>(als, ald, N * 4, 4, mint);
    gat_agg128<<<gAgg, B, 0, stream>>>(offsets, csr_src, bufH, als, ald, mint, b0, bufAcc, N);

    // ===== Layer 1 =====
    gemm_logits<128, 8, 4><<<gRows64, B, 0, stream>>>(bufAcc, W1, a_src1, a_dst1, bufH, als, ald, N);
    hipMemsetAsync(mint, 0x80, 8 * sizeof(int), stream);
    maxred<<<128, B, 0, stream>>>(als, ald, N * 4, 4, mint);
    gat_agg128<<<gAgg, B, 0, stream>>>(offsets, csr_src, bufH, als, ald, mint, b1, bufAcc, N);

    // ===== Layer 2 =====
    gemm_logits<40, 3, 1><<<gRows64, B, 0, stream>>>(bufAcc, W2, a_src2, a_dst2, bufH, als, ald, N);
    hipMemsetAsync(mint, 0x80, 8 * sizeof(int), stream);
    maxred<<<128, B, 0, stream>>>(als, ald, N, 1, mint);
    gat_agg40_lsm<<<gAgg, B, 0, stream>>>(offsets, csr_src, bufH, als, ald, mint, b2,
                                          (float*)d_out, N);
}

// Round 6
// 380.170 us; speedup vs baseline: 1.2010x; 1.2010x over previous
//
#include <hip/hip_runtime.h>
#include <hip/hip_fp16.h>
#include <math.h>

__device__ __forceinline__ int f2oi(float f) {
    int i = __float_as_int(f);
    return i >= 0 ? i : (i ^ 0x7FFFFFFF);
}
__device__ __forceinline__ float oi2f(int i) {
    return __int_as_float(i >= 0 ? i : (i ^ 0x7FFFFFFF));
}

// ---------- GEMM + fused logits + fused global-max ----------
// Hout[N,M](fp16) = X[N,128] @ W[M,128]^T ; als/ald[n,h] = <Hout[n,h,:], a>;
// mint[0..3]=max als per head, mint[4..7]=max ald per head (ordered-int atomicMax).
// Thread: 4 rows (rb+16q) x cols {32q+2*l16, +1} for q<NQ.
template<int M, int NQ, int H>
__global__ __launch_bounds__(256) void gemm_logits(const float* __restrict__ X,
                                                   const float* __restrict__ W,
                                                   const float* __restrict__ a_src,
                                                   const float* __restrict__ a_dst,
                                                   __half* __restrict__ Hout,
                                                   float* __restrict__ als,
                                                   float* __restrict__ ald,
                                                   int* __restrict__ mint, int N) {
    __shared__ float Wl[M * 128];
    for (int i = threadIdx.x; i < M * 32; i += 256) {
        int j = i >> 5, kg = i & 31;
        float4 w = reinterpret_cast<const float4*>(W)[i];
        int ks = (kg * 4) ^ (((j >> 1) & 7) << 2);
        *reinterpret_cast<float4*>(&Wl[j * 128 + ks]) = w;
    }
    __syncthreads();

    int l16 = threadIdx.x & 15;
    int rb = threadIdx.x >> 4;
    int wid = threadIdx.x >> 6;
    int base = blockIdx.x * 64;

    const float4* xr[4];
    int rows[4];
#pragma unroll
    for (int q = 0; q < 4; q++) {
        int row = base + rb + q * 16;
        rows[q] = row;
        int rc = row < N ? row : 0;
        xr[q] = reinterpret_cast<const float4*>(X + (long long)rc * 128);
    }

    float acc[4][NQ][2];
#pragma unroll
    for (int r = 0; r < 4; r++)
#pragma unroll
        for (int q = 0; q < NQ; q++) { acc[r][q][0] = 0.f; acc[r][q][1] = 0.f; }

#pragma unroll 4
    for (int kg = 0; kg < 32; kg++) {
        float4 xv0 = xr[0][kg];
        float4 xv1 = xr[1][kg];
        float4 xv2 = xr[2][kg];
        float4 xv3 = xr[3][kg];
#pragma unroll
        for (int q = 0; q < NQ; q++) {
            int j0 = 32 * q + 2 * l16;
            if (M == 128 || j0 < M) {
                int ks = (kg * 4) ^ ((l16 & 7) << 2);
                const float4 wv0 = *reinterpret_cast<const float4*>(&Wl[j0 * 128 + ks]);
                const float4 wv1 = *reinterpret_cast<const float4*>(&Wl[(j0 + 1) * 128 + ks]);
                acc[0][q][0] = fmaf(xv0.x, wv0.x, fmaf(xv0.y, wv0.y, fmaf(xv0.z, wv0.z, fmaf(xv0.w, wv0.w, acc[0][q][0]))));
                acc[1][q][0] = fmaf(xv1.x, wv0.x, fmaf(xv1.y, wv0.y, fmaf(xv1.z, wv0.z, fmaf(xv1.w, wv0.w, acc[1][q][0]))));
                acc[2][q][0] = fmaf(xv2.x, wv0.x, fmaf(xv2.y, wv0.y, fmaf(xv2.z, wv0.z, fmaf(xv2.w, wv0.w, acc[2][q][0]))));
                acc[3][q][0] = fmaf(xv3.x, wv0.x, fmaf(xv3.y, wv0.y, fmaf(xv3.z, wv0.z, fmaf(xv3.w, wv0.w, acc[3][q][0]))));
                acc[0][q][1] = fmaf(xv0.x, wv1.x, fmaf(xv0.y, wv1.y, fmaf(xv0.z, wv1.z, fmaf(xv0.w, wv1.w, acc[0][q][1]))));
                acc[1][q][1] = fmaf(xv1.x, wv1.x, fmaf(xv1.y, wv1.y, fmaf(xv1.z, wv1.z, fmaf(xv1.w, wv1.w, acc[1][q][1]))));
                acc[2][q][1] = fmaf(xv2.x, wv1.x, fmaf(xv2.y, wv1.y, fmaf(xv2.z, wv1.z, fmaf(xv2.w, wv1.w, acc[2][q][1]))));
                acc[3][q][1] = fmaf(xv3.x, wv1.x, fmaf(xv3.y, wv1.y, fmaf(xv3.z, wv1.z, fmaf(xv3.w, wv1.w, acc[3][q][1]))));
            }
        }
    }

    float asv[NQ][2], adv[NQ][2];
#pragma unroll
    for (int q = 0; q < NQ; q++) {
        int j0 = 32 * q + 2 * l16;
        asv[q][0] = (j0 < M) ? a_src[j0] : 0.f;
        asv[q][1] = (j0 + 1 < M) ? a_src[j0 + 1] : 0.f;
        adv[q][0] = (j0 < M) ? a_dst[j0] : 0.f;
        adv[q][1] = (j0 + 1 < M) ? a_dst[j0 + 1] : 0.f;
    }

    float tms[H], tmd[H];
#pragma unroll
    for (int h = 0; h < H; h++) { tms[h] = -INFINITY; tmd[h] = -INFINITY; }

#pragma unroll
    for (int qr = 0; qr < 4; qr++) {
        int row = rows[qr];
        float hs[H], hd[H];
#pragma unroll
        for (int h = 0; h < H; h++) { hs[h] = 0.f; hd[h] = 0.f; }
#pragma unroll
        for (int q = 0; q < NQ; q++) {
            int h = (H == 1) ? 0 : q;
            hs[h] = fmaf(acc[qr][q][0], asv[q][0], fmaf(acc[qr][q][1], asv[q][1], hs[h]));
            hd[h] = fmaf(acc[qr][q][0], adv[q][0], fmaf(acc[qr][q][1], adv[q][1], hd[h]));
        }
#pragma unroll
        for (int off = 8; off >= 1; off >>= 1) {
#pragma unroll
            for (int h = 0; h < H; h++) {
                hs[h] += __shfl_xor(hs[h], off, 64);
                hd[h] += __shfl_xor(hd[h], off, 64);
            }
        }
#pragma unroll
        for (int h = 0; h < H; h++) {
            tms[h] = fmaxf(tms[h], hs[h]);
            tmd[h] = fmaxf(tmd[h], hd[h]);
        }
        if (row < N) {
            if (l16 < H) als[row * H + l16] = hs[l16];
            if (l16 >= 8 && l16 < 8 + H) ald[row * H + (l16 - 8)] = hd[l16 - 8];
            __half2* hp = reinterpret_cast<__half2*>(Hout) + (long long)row * (M / 2);
#pragma unroll
            for (int q = 0; q < NQ; q++) {
                int j0 = 32 * q + 2 * l16;
                if (j0 < M) hp[j0 >> 1] = __floats2half2_rn(acc[qr][q][0], acc[qr][q][1]);
            }
        }
    }

    // wave-level max (tms uniform within l16 group; reduce across rb groups)
#pragma unroll
    for (int off = 32; off >= 16; off >>= 1) {
#pragma unroll
        for (int h = 0; h < H; h++) {
            tms[h] = fmaxf(tms[h], __shfl_xor(tms[h], off, 64));
            tmd[h] = fmaxf(tmd[h], __shfl_xor(tmd[h], off, 64));
        }
    }
    __syncthreads();                 // all waves done with Wl; reuse as scratch
    if ((threadIdx.x & 63) == 0) {
#pragma unroll
        for (int h = 0; h < H; h++) {
            Wl[wid * 16 + h] = tms[h];
            Wl[wid * 16 + 8 + h] = tmd[h];
        }
    }
    __syncthreads();
    if (threadIdx.x < H) {
        float v = fmaxf(fmaxf(Wl[threadIdx.x], Wl[16 + threadIdx.x]),
                        fmaxf(Wl[32 + threadIdx.x], Wl[48 + threadIdx.x]));
        atomicMax(&mint[threadIdx.x], f2oi(v));
    }
    if (threadIdx.x >= 8 && threadIdx.x < 8 + H) {
        int h = threadIdx.x - 8;
        float v = fmaxf(fmaxf(Wl[8 + h], Wl[24 + h]), fmaxf(Wl[40 + h], Wl[56 + h]));
        atomicMax(&mint[4 + h], f2oi(v));
    }
}

// ---------- CSR build ----------
__global__ void hist_dst(const int* __restrict__ dst, int E_real, int E_tot,
                         int* __restrict__ counts) {
    int e = blockIdx.x * blockDim.x + threadIdx.x;
    if (e >= E_tot) return;
    int d = (e < E_real) ? dst[e] : e - E_real;
    atomicAdd(&counts[d], 1);
}

__global__ __launch_bounds__(256) void scanA(const int* __restrict__ counts,
                                             int* __restrict__ offsets,
                                             int* __restrict__ blockTot, int N) {
    __shared__ int sh[256];
    int tid = threadIdx.x;
    int base = blockIdx.x * 1024 + tid * 4;
    int v0 = 0, v1 = 0, v2 = 0, v3 = 0;
    if (base + 0 < N) v0 = counts[base + 0];
    if (base + 1 < N) v1 = counts[base + 1];
    if (base + 2 < N) v2 = counts[base + 2];
    if (base + 3 < N) v3 = counts[base + 3];
    int s = v0 + v1 + v2 + v3;
    sh[tid] = s;
    __syncthreads();
    for (int off = 1; off < 256; off <<= 1) {
        int t = (tid >= off) ? sh[tid - off] : 0;
        __syncthreads();
        sh[tid] += t;
        __syncthreads();
    }
    int run = sh[tid] - s;
    if (base + 0 < N) { offsets[base + 0] = run; run += v0; }
    if (base + 1 < N) { offsets[base + 1] = run; run += v1; }
    if (base + 2 < N) { offsets[base + 2] = run; run += v2; }
    if (base + 3 < N) { offsets[base + 3] = run; }
    if (tid == 255) blockTot[blockIdx.x] = sh[255];
}

__global__ __launch_bounds__(256) void scanB(const int* __restrict__ blockTot,
                                             int* __restrict__ blockPre,
                                             int* __restrict__ offsets, int SB, int N) {
    __shared__ int sh[256];
    int tid = threadIdx.x;
    int v = (tid < SB) ? blockTot[tid] : 0;
    sh[tid] = v;
    __syncthreads();
    for (int off = 1; off < 256; off <<= 1) {
        int t = (tid >= off) ? sh[tid - off] : 0;
        __syncthreads();
        sh[tid] += t;
        __syncthreads();
    }
    blockPre[tid] = sh[tid] - v;
    if (tid == 255) offsets[N] = sh[255];
}

__global__ __launch_bounds__(256) void scanC(int* __restrict__ offsets,
                                             int* __restrict__ cursor,
                                             const int* __restrict__ blockPre, int N) {
    int pre = blockPre[blockIdx.x];
    int base = blockIdx.x * 1024 + threadIdx.x * 4;
#pragma unroll
    for (int j = 0; j < 4; j++) {
        int i = base + j;
        if (i < N) {
            int o = offsets[i] + pre;
            offsets[i] = o;
            cursor[i] = o;
        }
    }
}

__global__ void scatter_src(const int* __restrict__ src, const int* __restrict__ dst,
                            int E_real, int E_tot, int* __restrict__ cursor,
                            int* __restrict__ csr_src) {
    int e = blockIdx.x * blockDim.x + threadIdx.x;
    if (e >= E_tot) return;
    int s, d;
    if (e < E_real) { s = src[e]; d = dst[e]; } else { s = d = e - E_real; }
    int pos = atomicAdd(&cursor[d], 1);
    csr_src[pos] = s;
}

// ---------- fused GAT aggregate, layers 0/1 (H=4,C=32), fp16 h ----------
__global__ __launch_bounds__(256) void gat_agg128(const int* __restrict__ offsets,
                                                  const int* __restrict__ csr_src,
                                                  const __half* __restrict__ h,
                                                  const float* __restrict__ als,
                                                  const float* __restrict__ ald,
                                                  const int* __restrict__ mint,
                                                  const float* __restrict__ bias,
                                                  float* __restrict__ out, int N) {
    __shared__ float wlds[4][64][4];
    __shared__ int   slds[4][64];
    int wid = threadIdx.x >> 6;
    int lane = threadIdx.x & 63;
    int gwid = (blockIdx.x * 256 + threadIdx.x) >> 6;
    int nWaves = (gridDim.x * 256) >> 6;
    int hh = lane >> 4;
    const __half2* h2 = (const __half2*)h;
    const float4* als4 = (const float4*)als;
    const float4* ald4 = (const float4*)ald;
    float2 bv = ((const float2*)bias)[lane];

    float4 shift;
    {
        float v;
        v = oi2f(mint[0]) + oi2f(mint[4]); shift.x = v > 0.f ? v : 0.2f * v;
        v = oi2f(mint[1]) + oi2f(mint[5]); shift.y = v > 0.f ? v : 0.2f * v;
        v = oi2f(mint[2]) + oi2f(mint[6]); shift.z = v > 0.f ? v : 0.2f * v;
        v = oi2f(mint[3]) + oi2f(mint[7]); shift.w = v > 0.f ? v : 0.2f * v;
    }

    for (int n = gwid; n < N; n += nWaves) {
        int beg = offsets[n], end = offsets[n + 1];
        float4 adn = ald4[n];
        float accx = 0.f, accy = 0.f, den = 0.f;

        for (int c0 = beg; c0 < end; c0 += 64) {
            int e = c0 + lane;
            if (e < end) {
                int s = csr_src[e];
                float4 a4 = als4[s];
                float4 w; float v;
                v = a4.x + adn.x; v = v > 0.f ? v : 0.2f * v; w.x = __expf(v - shift.x);
                v = a4.y + adn.y; v = v > 0.f ? v : 0.2f * v; w.y = __expf(v - shift.y);
                v = a4.z + adn.z; v = v > 0.f ? v : 0.2f * v; w.z = __expf(v - shift.z);
                v = a4.w + adn.w; v = v > 0.f ? v : 0.2f * v; w.w = __expf(v - shift.w);
                *reinterpret_cast<float4*>(&wlds[wid][lane][0]) = w;
                slds[wid][lane] = s;
            }
            int cnt = end - c0; if (cnt > 64) cnt = 64;
            int p = 0;
            for (; p + 4 <= cnt; p += 4) {
                float w0 = wlds[wid][p][hh];     int s0 = slds[wid][p];
                float w1 = wlds[wid][p + 1][hh]; int s1 = slds[wid][p + 1];
                float w2 = wlds[wid][p + 2][hh]; int s2 = slds[wid][p + 2];
                float w3 = wlds[wid][p + 3][hh]; int s3 = slds[wid][p + 3];
                float2 f0 = __half22float2(h2[(size_t)s0 * 64 + lane]);
                float2 f1 = __half22float2(h2[(size_t)s1 * 64 + lane]);
                float2 f2 = __half22float2(h2[(size_t)s2 * 64 + lane]);
                float2 f3 = __half22float2(h2[(size_t)s3 * 64 + lane]);
                den += (w0 + w1) + (w2 + w3);
                accx = fmaf(f0.x, w0, fmaf(f1.x, w1, fmaf(f2.x, w2, fmaf(f3.x, w3, accx))));
                accy = fmaf(f0.y, w0, fmaf(f1.y, w1, fmaf(f2.y, w2, fmaf(f3.y, w3, accy))));
            }
            for (; p < cnt; ++p) {
                float w0 = wlds[wid][p][hh]; int s0 = slds[wid][p];
                float2 f0 = __half22float2(h2[(size_t)s0 * 64 + lane]);
                den += w0;
                accx = fmaf(f0.x, w0, accx);
                accy = fmaf(f0.y, w0, accy);
            }
        }
        float inv = 1.f / den;
        float r0 = accx * inv + bv.x;
        float r1 = accy * inv + bv.y;
        float2 o;
        o.x = r0 > 0.f ? r0 : expm1f(r0);
        o.y = r1 > 0.f ? r1 : expm1f(r1);
        ((float2*)out)[(size_t)n * 64 + lane] = o;
    }
}

// ---------- fused GAT aggregate + log_softmax, layer 2 (H=1,C=40), fp16 h ----------
__global__ __launch_bounds__(256) void gat_agg40_lsm(const int* __restrict__ offsets,
                                                     const int* __restrict__ csr_src,
                                                     const __half* __restrict__ h,
                                                     const float* __restrict__ als,
                                                     const float* __restrict__ ald,
                                                     const int* __restrict__ mint,
                                                     const float* __restrict__ b2,
                                                     float* __restrict__ out, int N) {
    __shared__ float wlds[4][64];
    __shared__ int   slds[4][64];
    int wid = threadIdx.x >> 6;
    int lane = threadIdx.x & 63;
    int gwid = (blockIdx.x * 256 + threadIdx.x) >> 6;
    int nWaves = (gridDim.x * 256) >> 6;

    float shift;
    {
        float v = oi2f(mint[0]) + oi2f(mint[4]);
        shift = v > 0.f ? v : 0.2f * v;
    }

    for (int n = gwid; n < N; n += nWaves) {
        int beg = offsets[n], end = offsets[n + 1];
        float adn = ald[n];
        float acc = 0.f, den = 0.f;

        for (int c0 = beg; c0 < end; c0 += 64) {
            int e = c0 + lane;
            if (e < end) {
                int s = csr_src[e];
                float v = als[s] + adn; v = v > 0.f ? v : 0.2f * v;
                wlds[wid][lane] = __expf(v - shift);
                slds[wid][lane] = s;
            }
            int cnt = end - c0; if (cnt > 64) cnt = 64;
            int p = 0;
            for (; p + 4 <= cnt; p += 4) {
                float w0 = wlds[wid][p];     int s0 = slds[wid][p];
                float w1 = wlds[wid][p + 1]; int s1 = slds[wid][p + 1];
                float w2 = wlds[wid][p + 2]; int s2 = slds[wid][p + 2];
                float w3 = wlds[wid][p + 3]; int s3 = slds[wid][p + 3];
                float h0 = (lane < 40) ? __half2float(h[(size_t)s0 * 40 + lane]) : 0.f;
                float h1 = (lane < 40) ? __half2float(h[(size_t)s1 * 40 + lane]) : 0.f;
                float h2v = (lane < 40) ? __half2float(h[(size_t)s2 * 40 + lane]) : 0.f;
                float h3 = (lane < 40) ? __half2float(h[(size_t)s3 * 40 + lane]) : 0.f;
                den += (w0 + w1) + (w2 + w3);
                acc = fmaf(h0, w0, fmaf(h1, w1, fmaf(h2v, w2, fmaf(h3, w3, acc))));
            }
            for (; p < cnt; ++p) {
                float w0 = wlds[wid][p]; int s0 = slds[wid][p];
                float h0 = (lane < 40) ? __half2float(h[(size_t)s0 * 40 + lane]) : 0.f;
                den += w0;
                acc = fmaf(h0, w0, acc);
            }
        }
        float val = (lane < 40) ? acc / den + b2[lane] : -INFINITY;
        float mx = val;
#pragma unroll
        for (int off = 32; off >= 1; off >>= 1) mx = fmaxf(mx, __shfl_xor(mx, off, 64));
        float pe = (lane < 40) ? __expf(val - mx) : 0.f;
        float sum = pe;
#pragma unroll
        for (int off = 32; off >= 1; off >>= 1) sum += __shfl_xor(sum, off, 64);
        if (lane < 40) out[n * 40 + lane] = val - mx - logf(sum);
    }
}

extern "C" void kernel_launch(void* const* d_in, const int* in_sizes, int n_in,
                              void* d_out, int out_size, void* d_ws, size_t ws_size,
                              hipStream_t stream) {
    const float* x      = (const float*)d_in[0];
    const int*   ei     = (const int*)d_in[1];
    const float* W0     = (const float*)d_in[2];
    const float* a_src0 = (const float*)d_in[3];
    const float* a_dst0 = (const float*)d_in[4];
    const float* b0     = (const float*)d_in[5];
    const float* W1     = (const float*)d_in[6];
    const float* a_src1 = (const float*)d_in[7];
    const float* a_dst1 = (const float*)d_in[8];
    const float* b1     = (const float*)d_in[9];
    const float* W2     = (const float*)d_in[10];
    const float* a_src2 = (const float*)d_in[11];
    const float* a_dst2 = (const float*)d_in[12];
    const float* b2     = (const float*)d_in[13];

    const int N = in_sizes[0] / 128;          // 50000
    const int E_real = in_sizes[1] / 2;       // 800000
    const int E_tot = E_real + N;
    const int* src = ei;
    const int* dst = ei + E_real;

    unsigned char* ws = (unsigned char*)d_ws;
    const size_t szH16 = (size_t)N * 128 * sizeof(__half);   // 12.8 MB
    const size_t szAcc = (size_t)N * 128 * sizeof(float);    // 25.6 MB
    __half* bufH    = (__half*)(ws);
    float* bufAcc   = (float*)(ws + szH16);
    float* als      = (float*)(ws + szH16 + szAcc);
    float* ald      = (float*)(ws + szH16 + szAcc + (size_t)N * 4 * sizeof(float));
    int*   offsets  = (int*)  (ws + szH16 + szAcc + (size_t)N * 8 * sizeof(float));
    int*   counts   = offsets + (N + 1);
    int*   cursor   = counts + N;
    int*   blockTot = cursor + N;
    int*   blockPre = blockTot + 256;
    int*   mint     = blockPre + 256;         // 24 ints (8 per layer)
    int*   csr_src  = mint + 24;              // E_tot ints

    const int B = 256;
    const int gRows64 = (N + 63) / 64;
    const int gEdge = (E_tot + B - 1) / B;
    const int SB    = (N + 1023) / 1024;
    const int gAgg  = 2048;

    // ===== init + CSR build (once) =====
    hipMemsetAsync(mint, 0x80, 24 * sizeof(int), stream);   // ~ -3.4e38 sentinel in f2oi space
    hipMemsetAsync(counts, 0, (size_t)N * sizeof(int), stream);
    hist_dst<<<gEdge, B, 0, stream>>>(dst, E_real, E_tot, counts);
    scanA<<<SB, B, 0, stream>>>(counts, offsets, blockTot, N);
    scanB<<<1, B, 0, stream>>>(blockTot, blockPre, offsets, SB, N);
    scanC<<<SB, B, 0, stream>>>(offsets, cursor, blockPre, N);
    scatter_src<<<gEdge, B, 0, stream>>>(src, dst, E_real, E_tot, cursor, csr_src);

    // ===== Layer 0 =====
    gemm_logits<128, 4, 4><<<gRows64, B, 0, stream>>>(x, W0, a_src0, a_dst0, bufH, als, ald, mint, N);
    gat_agg128<<<gAgg, B, 0, stream>>>(offsets, csr_src, bufH, als, ald, mint, b0, bufAcc, N);

    // ===== Layer 1 =====
    gemm_logits<128, 4, 4><<<gRows64, B, 0, stream>>>(bufAcc, W1, a_src1, a_dst1, bufH, als, ald, mint + 8, N);
    gat_agg128<<<gAgg, B, 0, stream>>>(offsets, csr_src, bufH, als, ald, mint + 8, b1, bufAcc, N);

    // ===== Layer 2 =====
    gemm_logits<40, 2, 1><<<gRows64, B, 0, stream>>>(bufAcc, W2, a_src2, a_dst2, bufH, als, ald, mint + 16, N);
    gat_agg40_lsm<<<gAgg, B, 0, stream>>>(offsets, csr_src, bufH, als, ald, mint + 16, b2,
                                          (float*)d_out, N);
}

// Round 7
// 307.386 us; speedup vs baseline: 1.4854x; 1.2368x over previous
//
#include <hip/hip_runtime.h>
#include <hip/hip_fp16.h>
#include <math.h>

__device__ __forceinline__ int f2oi(float f) {
    int i = __float_as_int(f);
    return i >= 0 ? i : (i ^ 0x7FFFFFFF);
}
__device__ __forceinline__ float oi2f(int i) {
    return __int_as_float(i >= 0 ? i : (i ^ 0x7FFFFFFF));
}

// ---------- GEMM + fused logits + fused global-max ----------
template<int M, int NQ, int H>
__global__ __launch_bounds__(256) void gemm_logits(const float* __restrict__ X,
                                                   const float* __restrict__ W,
                                                   const float* __restrict__ a_src,
                                                   const float* __restrict__ a_dst,
                                                   __half* __restrict__ Hout,
                                                   float* __restrict__ als,
                                                   float* __restrict__ ald,
                                                   int* __restrict__ mint, int N) {
    __shared__ float Wl[M * 128];
    for (int i = threadIdx.x; i < M * 32; i += 256) {
        int j = i >> 5, kg = i & 31;
        float4 w = reinterpret_cast<const float4*>(W)[i];
        int ks = (kg * 4) ^ (((j >> 1) & 7) << 2);
        *reinterpret_cast<float4*>(&Wl[j * 128 + ks]) = w;
    }
    __syncthreads();

    int l16 = threadIdx.x & 15;
    int rb = threadIdx.x >> 4;
    int wid = threadIdx.x >> 6;
    int base = blockIdx.x * 64;

    const float4* xr[4];
    int rows[4];
#pragma unroll
    for (int q = 0; q < 4; q++) {
        int row = base + rb + q * 16;
        rows[q] = row;
        int rc = row < N ? row : 0;
        xr[q] = reinterpret_cast<const float4*>(X + (long long)rc * 128);
    }

    float acc[4][NQ][2];
#pragma unroll
    for (int r = 0; r < 4; r++)
#pragma unroll
        for (int q = 0; q < NQ; q++) { acc[r][q][0] = 0.f; acc[r][q][1] = 0.f; }

#pragma unroll 4
    for (int kg = 0; kg < 32; kg++) {
        float4 xv0 = xr[0][kg];
        float4 xv1 = xr[1][kg];
        float4 xv2 = xr[2][kg];
        float4 xv3 = xr[3][kg];
#pragma unroll
        for (int q = 0; q < NQ; q++) {
            int j0 = 32 * q + 2 * l16;
            if (M == 128 || j0 < M) {
                int ks = (kg * 4) ^ ((l16 & 7) << 2);
                const float4 wv0 = *reinterpret_cast<const float4*>(&Wl[j0 * 128 + ks]);
                const float4 wv1 = *reinterpret_cast<const float4*>(&Wl[(j0 + 1) * 128 + ks]);
                acc[0][q][0] = fmaf(xv0.x, wv0.x, fmaf(xv0.y, wv0.y, fmaf(xv0.z, wv0.z, fmaf(xv0.w, wv0.w, acc[0][q][0]))));
                acc[1][q][0] = fmaf(xv1.x, wv0.x, fmaf(xv1.y, wv0.y, fmaf(xv1.z, wv0.z, fmaf(xv1.w, wv0.w, acc[1][q][0]))));
                acc[2][q][0] = fmaf(xv2.x, wv0.x, fmaf(xv2.y, wv0.y, fmaf(xv2.z, wv0.z, fmaf(xv2.w, wv0.w, acc[2][q][0]))));
                acc[3][q][0] = fmaf(xv3.x, wv0.x, fmaf(xv3.y, wv0.y, fmaf(xv3.z, wv0.z, fmaf(xv3.w, wv0.w, acc[3][q][0]))));
                acc[0][q][1] = fmaf(xv0.x, wv1.x, fmaf(xv0.y, wv1.y, fmaf(xv0.z, wv1.z, fmaf(xv0.w, wv1.w, acc[0][q][1]))));
                acc[1][q][1] = fmaf(xv1.x, wv1.x, fmaf(xv1.y, wv1.y, fmaf(xv1.z, wv1.z, fmaf(xv1.w, wv1.w, acc[1][q][1]))));
                acc[2][q][1] = fmaf(xv2.x, wv1.x, fmaf(xv2.y, wv1.y, fmaf(xv2.z, wv1.z, fmaf(xv2.w, wv1.w, acc[2][q][1]))));
                acc[3][q][1] = fmaf(xv3.x, wv1.x, fmaf(xv3.y, wv1.y, fmaf(xv3.z, wv1.z, fmaf(xv3.w, wv1.w, acc[3][q][1]))));
            }
        }
    }

    float asv[NQ][2], adv[NQ][2];
#pragma unroll
    for (int q = 0; q < NQ; q++) {
        int j0 = 32 * q + 2 * l16;
        asv[q][0] = (j0 < M) ? a_src[j0] : 0.f;
        asv[q][1] = (j0 + 1 < M) ? a_src[j0 + 1] : 0.f;
        adv[q][0] = (j0 < M) ? a_dst[j0] : 0.f;
        adv[q][1] = (j0 + 1 < M) ? a_dst[j0 + 1] : 0.f;
    }

    float tms[H], tmd[H];
#pragma unroll
    for (int h = 0; h < H; h++) { tms[h] = -INFINITY; tmd[h] = -INFINITY; }

#pragma unroll
    for (int qr = 0; qr < 4; qr++) {
        int row = rows[qr];
        float hs[H], hd[H];
#pragma unroll
        for (int h = 0; h < H; h++) { hs[h] = 0.f; hd[h] = 0.f; }
#pragma unroll
        for (int q = 0; q < NQ; q++) {
            int h = (H == 1) ? 0 : q;
            hs[h] = fmaf(acc[qr][q][0], asv[q][0], fmaf(acc[qr][q][1], asv[q][1], hs[h]));
            hd[h] = fmaf(acc[qr][q][0], adv[q][0], fmaf(acc[qr][q][1], adv[q][1], hd[h]));
        }
#pragma unroll
        for (int off = 8; off >= 1; off >>= 1) {
#pragma unroll
            for (int h = 0; h < H; h++) {
                hs[h] += __shfl_xor(hs[h], off, 64);
                hd[h] += __shfl_xor(hd[h], off, 64);
            }
        }
#pragma unroll
        for (int h = 0; h < H; h++) {
            tms[h] = fmaxf(tms[h], hs[h]);
            tmd[h] = fmaxf(tmd[h], hd[h]);
        }
        if (row < N) {
            if (l16 < H) als[row * H + l16] = hs[l16];
            if (l16 >= 8 && l16 < 8 + H) ald[row * H + (l16 - 8)] = hd[l16 - 8];
            __half2* hp = reinterpret_cast<__half2*>(Hout) + (long long)row * (M / 2);
#pragma unroll
            for (int q = 0; q < NQ; q++) {
                int j0 = 32 * q + 2 * l16;
                if (j0 < M) hp[j0 >> 1] = __floats2half2_rn(acc[qr][q][0], acc[qr][q][1]);
            }
        }
    }

#pragma unroll
    for (int off = 32; off >= 16; off >>= 1) {
#pragma unroll
        for (int h = 0; h < H; h++) {
            tms[h] = fmaxf(tms[h], __shfl_xor(tms[h], off, 64));
            tmd[h] = fmaxf(tmd[h], __shfl_xor(tmd[h], off, 64));
        }
    }
    __syncthreads();
    if ((threadIdx.x & 63) == 0) {
#pragma unroll
        for (int h = 0; h < H; h++) {
            Wl[wid * 16 + h] = tms[h];
            Wl[wid * 16 + 8 + h] = tmd[h];
        }
    }
    __syncthreads();
    if (threadIdx.x < H) {
        float v = fmaxf(fmaxf(Wl[threadIdx.x], Wl[16 + threadIdx.x]),
                        fmaxf(Wl[32 + threadIdx.x], Wl[48 + threadIdx.x]));
        atomicMax(&mint[threadIdx.x], f2oi(v));
    }
    if (threadIdx.x >= 8 && threadIdx.x < 8 + H) {
        int h = threadIdx.x - 8;
        float v = fmaxf(fmaxf(Wl[8 + h], Wl[24 + h]), fmaxf(Wl[40 + h], Wl[56 + h]));
        atomicMax(&mint[4 + h], f2oi(v));
    }
}

// ---------- atomic-free CSR build (two-level counting sort) ----------
// Coarse bucket = dst >> 6 (64 nodes per bucket). NB <= 1024, NBLK <= 256.

__global__ __launch_bounds__(256) void p1_hist(const int* __restrict__ src,
                                               const int* __restrict__ dst,
                                               int E_real, int E_tot, int NB, int NBLK,
                                               int EPB, int* __restrict__ cntmat) {
    __shared__ int hist[1024];
    for (int i = threadIdx.x; i < NB; i += 256) hist[i] = 0;
    __syncthreads();
    int e0 = blockIdx.x * EPB;
    int e1 = min(e0 + EPB, E_tot);
    for (int e = e0 + threadIdx.x; e < e1; e += 256) {
        int d = (e < E_real) ? dst[e] : e - E_real;
        atomicAdd(&hist[d >> 6], 1);
    }
    __syncthreads();
    for (int b = threadIdx.x; b < NB; b += 256)
        cntmat[b * NBLK + blockIdx.x] = hist[b];
}

// per-bucket exclusive scan over blocks (in place), total -> colTot[b]
__global__ __launch_bounds__(256) void p_scancols(int* __restrict__ cntmat,
                                                  int* __restrict__ colTot, int NBLK) {
    __shared__ int sh[256];
    int b = blockIdx.x;
    int t = threadIdx.x;
    if (t < NBLK) sh[t] = cntmat[b * NBLK + t];
    __syncthreads();
    if (t == 0) {
        int run = 0;
        for (int i = 0; i < NBLK; i++) { int v = sh[i]; sh[i] = run; run += v; }
        colTot[b] = run;
    }
    __syncthreads();
    if (t < NBLK) cntmat[b * NBLK + t] = sh[t];
}

// exclusive scan of colTot -> coarseOff[0..NB]; also offsets[N] = E_tot
__global__ __launch_bounds__(256) void p_scancoarse(const int* __restrict__ colTot,
                                                    int* __restrict__ coarseOff,
                                                    int* __restrict__ offsets,
                                                    int NB, int N, int E_tot) {
    __shared__ int sh[256];
    int t = threadIdx.x, base = t * 4;
    int v0 = 0, v1 = 0, v2 = 0, v3 = 0;
    if (base + 0 < NB) v0 = colTot[base + 0];
    if (base + 1 < NB) v1 = colTot[base + 1];
    if (base + 2 < NB) v2 = colTot[base + 2];
    if (base + 3 < NB) v3 = colTot[base + 3];
    int s = v0 + v1 + v2 + v3;
    sh[t] = s;
    __syncthreads();
    for (int off = 1; off < 256; off <<= 1) {
        int u = (t >= off) ? sh[t - off] : 0;
        __syncthreads();
        sh[t] += u;
        __syncthreads();
    }
    int run = sh[t] - s;
    if (base + 0 < NB) { coarseOff[base + 0] = run; run += v0; }
    if (base + 1 < NB) { coarseOff[base + 1] = run; run += v1; }
    if (base + 2 < NB) { coarseOff[base + 2] = run; run += v2; }
    if (base + 3 < NB) { coarseOff[base + 3] = run; }
    if (t == 255) { coarseOff[NB] = sh[255]; offsets[N] = E_tot; }
}

// partition edges into coarse-bucket regions (block-private sub-ranges, LDS cursors)
__global__ __launch_bounds__(256) void p2_scatter(const int* __restrict__ src,
                                                  const int* __restrict__ dst,
                                                  int E_real, int E_tot, int NB, int NBLK,
                                                  int EPB, const int* __restrict__ cntmat,
                                                  const int* __restrict__ coarseOff,
                                                  int2* __restrict__ pairs) {
    __shared__ int cur[1024];
    for (int b = threadIdx.x; b < NB; b += 256)
        cur[b] = coarseOff[b] + cntmat[b * NBLK + blockIdx.x];
    __syncthreads();
    int e0 = blockIdx.x * EPB;
    int e1 = min(e0 + EPB, E_tot);
    for (int e = e0 + threadIdx.x; e < e1; e += 256) {
        int s, d;
        if (e < E_real) { s = src[e]; d = dst[e]; } else { s = d = e - E_real; }
        int pos = atomicAdd(&cur[d >> 6], 1);
        pairs[pos] = make_int2(s, d);
    }
}

// per-bucket exact counting sort -> csr_src + offsets
__global__ __launch_bounds__(256) void p3_bucket(const int2* __restrict__ pairs,
                                                 const int* __restrict__ coarseOff,
                                                 int NB, int N, int* __restrict__ offsets,
                                                 int* __restrict__ csr_src) {
    __shared__ int lh[64], lc[64];
    int b = blockIdx.x;
    int beg = coarseOff[b], end = coarseOff[b + 1];
    int t = threadIdx.x;
    if (t < 64) lh[t] = 0;
    __syncthreads();
    for (int i = beg + t; i < end; i += 256)
        atomicAdd(&lh[pairs[i].y & 63], 1);
    __syncthreads();
    if (t < 64) {
        int v = lh[t];
        int run = v;
#pragma unroll
        for (int off = 1; off < 64; off <<= 1) {
            int o = __shfl_up(run, off, 64);
            if (t >= off) run += o;
        }
        int ex = run - v;        // exclusive prefix
        lc[t] = ex;
        int node = b * 64 + t;
        if (node < N) offsets[node] = beg + ex;
    }
    __syncthreads();
    for (int i = beg + t; i < end; i += 256) {
        int2 p = pairs[i];
        int pos = atomicAdd(&lc[p.y & 63], 1);
        csr_src[beg + pos] = p.x;
    }
}

// ---------- fused GAT aggregate, layers 0/1 (H=4,C=32), fp16 h ----------
__global__ __launch_bounds__(256) void gat_agg128(const int* __restrict__ offsets,
                                                  const int* __restrict__ csr_src,
                                                  const __half* __restrict__ h,
                                                  const float* __restrict__ als,
                                                  const float* __restrict__ ald,
                                                  const int* __restrict__ mint,
                                                  const float* __restrict__ bias,
                                                  float* __restrict__ out, int N) {
    __shared__ float wlds[4][64][4];
    __shared__ int   slds[4][64];
    int wid = threadIdx.x >> 6;
    int lane = threadIdx.x & 63;
    int gwid = (blockIdx.x * 256 + threadIdx.x) >> 6;
    int nWaves = (gridDim.x * 256) >> 6;
    int hh = lane >> 4;
    const __half2* h2 = (const __half2*)h;
    const float4* als4 = (const float4*)als;
    const float4* ald4 = (const float4*)ald;
    float2 bv = ((const float2*)bias)[lane];

    float4 shift;
    {
        float v;
        v = oi2f(mint[0]) + oi2f(mint[4]); shift.x = v > 0.f ? v : 0.2f * v;
        v = oi2f(mint[1]) + oi2f(mint[5]); shift.y = v > 0.f ? v : 0.2f * v;
        v = oi2f(mint[2]) + oi2f(mint[6]); shift.z = v > 0.f ? v : 0.2f * v;
        v = oi2f(mint[3]) + oi2f(mint[7]); shift.w = v > 0.f ? v : 0.2f * v;
    }

    for (int n = gwid; n < N; n += nWaves) {
        int beg = offsets[n], end = offsets[n + 1];
        float4 adn = ald4[n];
        float accx = 0.f, accy = 0.f, den = 0.f;

        for (int c0 = beg; c0 < end; c0 += 64) {
            int e = c0 + lane;
            if (e < end) {
                int s = csr_src[e];
                float4 a4 = als4[s];
                float4 w; float v;
                v = a4.x + adn.x; v = v > 0.f ? v : 0.2f * v; w.x = __expf(v - shift.x);
                v = a4.y + adn.y; v = v > 0.f ? v : 0.2f * v; w.y = __expf(v - shift.y);
                v = a4.z + adn.z; v = v > 0.f ? v : 0.2f * v; w.z = __expf(v - shift.z);
                v = a4.w + adn.w; v = v > 0.f ? v : 0.2f * v; w.w = __expf(v - shift.w);
                *reinterpret_cast<float4*>(&wlds[wid][lane][0]) = w;
                slds[wid][lane] = s;
            }
            int cnt = end - c0; if (cnt > 64) cnt = 64;
            int p = 0;
            for (; p + 4 <= cnt; p += 4) {
                float w0 = wlds[wid][p][hh];     int s0 = slds[wid][p];
                float w1 = wlds[wid][p + 1][hh]; int s1 = slds[wid][p + 1];
                float w2 = wlds[wid][p + 2][hh]; int s2 = slds[wid][p + 2];
                float w3 = wlds[wid][p + 3][hh]; int s3 = slds[wid][p + 3];
                float2 f0 = __half22float2(h2[(size_t)s0 * 64 + lane]);
                float2 f1 = __half22float2(h2[(size_t)s1 * 64 + lane]);
                float2 f2 = __half22float2(h2[(size_t)s2 * 64 + lane]);
                float2 f3 = __half22float2(h2[(size_t)s3 * 64 + lane]);
                den += (w0 + w1) + (w2 + w3);
                accx = fmaf(f0.x, w0, fmaf(f1.x, w1, fmaf(f2.x, w2, fmaf(f3.x, w3, accx))));
                accy = fmaf(f0.y, w0, fmaf(f1.y, w1, fmaf(f2.y, w2, fmaf(f3.y, w3, accy))));
            }
            for (; p < cnt; ++p) {
                float w0 = wlds[wid][p][hh]; int s0 = slds[wid][p];
                float2 f0 = __half22float2(h2[(size_t)s0 * 64 + lane]);
                den += w0;
                accx = fmaf(f0.x, w0, accx);
                accy = fmaf(f0.y, w0, accy);
            }
        }
        float inv = 1.f / den;
        float r0 = accx * inv + bv.x;
        float r1 = accy * inv + bv.y;
        float2 o;
        o.x = r0 > 0.f ? r0 : expm1f(r0);
        o.y = r1 > 0.f ? r1 : expm1f(r1);
        ((float2*)out)[(size_t)n * 64 + lane] = o;
    }
}

// ---------- fused GAT aggregate + log_softmax, layer 2 (H=1,C=40), fp16 h ----------
__global__ __launch_bounds__(256) void gat_agg40_lsm(const int* __restrict__ offsets,
                                                     const int* __restrict__ csr_src,
                                                     const __half* __restrict__ h,
                                                     const float* __restrict__ als,
                                                     const float* __restrict__ ald,
                                                     const int* __restrict__ mint,
                                                     const float* __restrict__ b2,
                                                     float* __restrict__ out, int N) {
    __shared__ float wlds[4][64];
    __shared__ int   slds[4][64];
    int wid = threadIdx.x >> 6;
    int lane = threadIdx.x & 63;
    int gwid = (blockIdx.x * 256 + threadIdx.x) >> 6;
    int nWaves = (gridDim.x * 256) >> 6;

    float shift;
    {
        float v = oi2f(mint[0]) + oi2f(mint[4]);
        shift = v > 0.f ? v : 0.2f * v;
    }

    for (int n = gwid; n < N; n += nWaves) {
        int beg = offsets[n], end = offsets[n + 1];
        float adn = ald[n];
        float acc = 0.f, den = 0.f;

        for (int c0 = beg; c0 < end; c0 += 64) {
            int e = c0 + lane;
            if (e < end) {
                int s = csr_src[e];
                float v = als[s] + adn; v = v > 0.f ? v : 0.2f * v;
                wlds[wid][lane] = __expf(v - shift);
                slds[wid][lane] = s;
            }
            int cnt = end - c0; if (cnt > 64) cnt = 64;
            int p = 0;
            for (; p + 4 <= cnt; p += 4) {
                float w0 = wlds[wid][p];     int s0 = slds[wid][p];
                float w1 = wlds[wid][p + 1]; int s1 = slds[wid][p + 1];
                float w2 = wlds[wid][p + 2]; int s2 = slds[wid][p + 2];
                float w3 = wlds[wid][p + 3]; int s3 = slds[wid][p + 3];
                float h0 = (lane < 40) ? __half2float(h[(size_t)s0 * 40 + lane]) : 0.f;
                float h1 = (lane < 40) ? __half2float(h[(size_t)s1 * 40 + lane]) : 0.f;
                float h2v = (lane < 40) ? __half2float(h[(size_t)s2 * 40 + lane]) : 0.f;
                float h3 = (lane < 40) ? __half2float(h[(size_t)s3 * 40 + lane]) : 0.f;
                den += (w0 + w1) + (w2 + w3);
                acc = fmaf(h0, w0, fmaf(h1, w1, fmaf(h2v, w2, fmaf(h3, w3, acc))));
            }
            for (; p < cnt; ++p) {
                float w0 = wlds[wid][p]; int s0 = slds[wid][p];
                float h0 = (lane < 40) ? __half2float(h[(size_t)s0 * 40 + lane]) : 0.f;
                den += w0;
                acc = fmaf(h0, w0, acc);
            }
        }
        float val = (lane < 40) ? acc / den + b2[lane] : -INFINITY;
        float mx = val;
#pragma unroll
        for (int off = 32; off >= 1; off >>= 1) mx = fmaxf(mx, __shfl_xor(mx, off, 64));
        float pe = (lane < 40) ? __expf(val - mx) : 0.f;
        float sum = pe;
#pragma unroll
        for (int off = 32; off >= 1; off >>= 1) sum += __shfl_xor(sum, off, 64);
        if (lane < 40) out[n * 40 + lane] = val - mx - logf(sum);
    }
}

extern "C" void kernel_launch(void* const* d_in, const int* in_sizes, int n_in,
                              void* d_out, int out_size, void* d_ws, size_t ws_size,
                              hipStream_t stream) {
    const float* x      = (const float*)d_in[0];
    const int*   ei     = (const int*)d_in[1];
    const float* W0     = (const float*)d_in[2];
    const float* a_src0 = (const float*)d_in[3];
    const float* a_dst0 = (const float*)d_in[4];
    const float* b0     = (const float*)d_in[5];
    const float* W1     = (const float*)d_in[6];
    const float* a_src1 = (const float*)d_in[7];
    const float* a_dst1 = (const float*)d_in[8];
    const float* b1     = (const float*)d_in[9];
    const float* W2     = (const float*)d_in[10];
    const float* a_src2 = (const float*)d_in[11];
    const float* a_dst2 = (const float*)d_in[12];
    const float* b2     = (const float*)d_in[13];

    const int N = in_sizes[0] / 128;          // 50000
    const int E_real = in_sizes[1] / 2;       // 800000
    const int E_tot = E_real + N;
    const int* src = ei;
    const int* dst = ei + E_real;

    const int EPB  = 4096;
    const int NBLK = (E_tot + EPB - 1) / EPB; // 208  (<=256 required)
    const int NB   = (N + 63) >> 6;           // 782  (<=1024 required)

    unsigned char* ws = (unsigned char*)d_ws;
    const size_t szH16 = (size_t)N * 128 * sizeof(__half);   // 12.8 MB
    const size_t szAcc = (size_t)N * 128 * sizeof(float);    // 25.6 MB
    size_t off = 0;
    __half* bufH    = (__half*)(ws + off); off += szH16;
    float*  bufAcc  = (float*)(ws + off);  off += szAcc;
    int2*   pairs   = (int2*)(ws + off);   off += (size_t)E_tot * sizeof(int2);   // 6.8 MB
    int*    csr_src = (int*)(ws + off);    off += (size_t)E_tot * sizeof(int);    // 3.4 MB
    float*  als     = (float*)(ws + off);  off += (size_t)N * 4 * sizeof(float);
    float*  ald     = (float*)(ws + off);  off += (size_t)N * 4 * sizeof(float);
    int*    cntmat  = (int*)(ws + off);    off += (size_t)NB * NBLK * sizeof(int);
    int*    colTot  = (int*)(ws + off);    off += (size_t)NB * sizeof(int);
    int*    coarseOff = (int*)(ws + off);  off += (size_t)(NB + 1) * sizeof(int);
    int*    offsets = (int*)(ws + off);    off += (size_t)(N + 1) * sizeof(int);
    int*    mint    = (int*)(ws + off);    off += 24 * sizeof(int);

    const int B = 256;
    const int gRows64 = (N + 63) / 64;
    const int gAgg  = 2048;

    // ===== CSR build (atomic-free, two-level counting sort) =====
    hipMemsetAsync(mint, 0x80, 24 * sizeof(int), stream);
    p1_hist<<<NBLK, B, 0, stream>>>(src, dst, E_real, E_tot, NB, NBLK, EPB, cntmat);
    p_scancols<<<NB, B, 0, stream>>>(cntmat, colTot, NBLK);
    p_scancoarse<<<1, B, 0, stream>>>(colTot, coarseOff, offsets, NB, N, E_tot);
    p2_scatter<<<NBLK, B, 0, stream>>>(src, dst, E_real, E_tot, NB, NBLK, EPB, cntmat, coarseOff, pairs);
    p3_bucket<<<NB, B, 0, stream>>>(pairs, coarseOff, NB, N, offsets, csr_src);

    // ===== Layer 0 =====
    gemm_logits<128, 4, 4><<<gRows64, B, 0, stream>>>(x, W0, a_src0, a_dst0, bufH, als, ald, mint, N);
    gat_agg128<<<gAgg, B, 0, stream>>>(offsets, csr_src, bufH, als, ald, mint, b0, bufAcc, N);

    // ===== Layer 1 =====
    gemm_logits<128, 4, 4><<<gRows64, B, 0, stream>>>(bufAcc, W1, a_src1, a_dst1, bufH, als, ald, mint + 8, N);
    gat_agg128<<<gAgg, B, 0, stream>>>(offsets, csr_src, bufH, als, ald, mint + 8, b1, bufAcc, N);

    // ===== Layer 2 =====
    gemm_logits<40, 2, 1><<<gRows64, B, 0, stream>>>(bufAcc, W2, a_src2, a_dst2, bufH, als, ald, mint + 16, N);
    gat_agg40_lsm<<<gAgg, B, 0, stream>>>(offsets, csr_src, bufH, als, ald, mint + 16, b2,
                                          (float*)d_out, N);
}

// Round 8
// 238.051 us; speedup vs baseline: 1.9180x; 1.2913x over previous
//
#include <hip/hip_runtime.h>
#include <hip/hip_fp16.h>
#include <math.h>

typedef _Float16 f16x8 __attribute__((ext_vector_type(8)));
typedef _Float16 f16x4 __attribute__((ext_vector_type(4)));
typedef float f32x4 __attribute__((ext_vector_type(4)));

__device__ __forceinline__ int f2oi(float f) {
    int i = __float_as_int(f);
    return i >= 0 ? i : (i ^ 0x7FFFFFFF);
}
__device__ __forceinline__ float oi2f(int i) {
    return __int_as_float(i >= 0 ? i : (i ^ 0x7FFFFFFF));
}

// ---------- MFMA GEMM + fused logits + fused global-max ----------
// Hout[N,Mout](fp16) = X[N,128] @ W[Mout,128]^T, fp32 accum via mfma 16x16x32_f16.
// Block: 256 thr (4 waves) x 128 rows. Wave: 2 row-tiles x MT col-tiles.
// Epilogue: D -> LDS (swizzled) -> coalesced store + logits + per-head max.
template<int MT, int H>
__global__ __launch_bounds__(256) void gemm_mfma(const float* __restrict__ X,
                                                 const float* __restrict__ W,
                                                 const float* __restrict__ a_src,
                                                 const float* __restrict__ a_dst,
                                                 __half* __restrict__ Hout, int Mout,
                                                 float* __restrict__ als,
                                                 float* __restrict__ ald,
                                                 int* __restrict__ mint, int N) {
    constexpr int LDSB = (MT * 4096 > 16384) ? MT * 4096 : 16384;
    constexpr int HST = (MT == 8) ? 256 : 128;     // hlds row stride (bytes)
    __shared__ char ldsb[LDSB];
    __shared__ int lmax[8];

    int tid = threadIdx.x;
    if (tid < 8) lmax[tid] = (int)0x80000000;

    // ---- stage W as fp16 into LDS (16B-chunk XOR swizzle by row) ----
    const int nf4 = 16 * MT * 32;                  // float4s
    for (int idx = tid; idx < nf4; idx += 256) {
        int r = idx >> 5, c = idx & 31;
        float4 w = (r < Mout) ? reinterpret_cast<const float4*>(W)[(size_t)r * 32 + c]
                              : make_float4(0.f, 0.f, 0.f, 0.f);
        f16x4 hv;
        hv[0] = (_Float16)w.x; hv[1] = (_Float16)w.y;
        hv[2] = (_Float16)w.z; hv[3] = (_Float16)w.w;
        int byte = r * 256 + ((c * 8) ^ ((r & 7) << 4));
        *reinterpret_cast<f16x4*>(&ldsb[byte]) = hv;
    }
    __syncthreads();

    // ---- MFMA main loop ----
    int l = tid & 63, wv = tid >> 6;
    int lr = l & 15, lk = l >> 4;
    f32x4 acc[2][MT];
#pragma unroll
    for (int rt = 0; rt < 2; rt++)
#pragma unroll
        for (int c = 0; c < MT; c++) acc[rt][c] = (f32x4){0.f, 0.f, 0.f, 0.f};

    const float* xp[2];
#pragma unroll
    for (int rt = 0; rt < 2; rt++) {
        int rg = blockIdx.x * 128 + rt * 64 + wv * 16 + lr;
        if (rg >= N) rg = N - 1;
        xp[rt] = X + (size_t)rg * 128 + lk * 8;
    }

#pragma unroll
    for (int k0 = 0; k0 < 128; k0 += 32) {
        f16x8 a[2];
#pragma unroll
        for (int rt = 0; rt < 2; rt++) {
            float4 x0 = *reinterpret_cast<const float4*>(xp[rt] + k0);
            float4 x1 = *reinterpret_cast<const float4*>(xp[rt] + k0 + 4);
            a[rt][0] = (_Float16)x0.x; a[rt][1] = (_Float16)x0.y;
            a[rt][2] = (_Float16)x0.z; a[rt][3] = (_Float16)x0.w;
            a[rt][4] = (_Float16)x1.x; a[rt][5] = (_Float16)x1.y;
            a[rt][6] = (_Float16)x1.z; a[rt][7] = (_Float16)x1.w;
        }
#pragma unroll
        for (int c = 0; c < MT; c++) {
            int n = 16 * c + lr;
            int byte = n * 256 + (((k0 + lk * 8) * 2) ^ ((n & 7) << 4));
            f16x8 b = *reinterpret_cast<const f16x8*>(&ldsb[byte]);
            acc[0][c] = __builtin_amdgcn_mfma_f32_16x16x32_f16(a[0], b, acc[0][c], 0, 0, 0);
            acc[1][c] = __builtin_amdgcn_mfma_f32_16x16x32_f16(a[1], b, acc[1][c], 0, 0, 0);
        }
    }
    __syncthreads();   // done reading W; reuse LDS for h-tile

    // ---- D -> LDS fp16 (swizzled 16B chunks by row) ----
#pragma unroll
    for (int rt = 0; rt < 2; rt++)
#pragma unroll
        for (int c = 0; c < MT; c++)
#pragma unroll
            for (int r = 0; r < 4; r++) {
                int rowl = rt * 64 + wv * 16 + lk * 4 + r;
                int col = 16 * c + lr;
                int byte = rowl * HST + ((col * 2) ^ ((rowl & 7) << 4));
                *reinterpret_cast<__half*>(&ldsb[byte]) = __float2half(acc[rt][c][r]);
            }
    __syncthreads();

    // ---- readback: coalesced fp16 store + logits + block max ----
    int row = tid >> 1, seg = tid & 1;
    int rowg = blockIdx.x * 128 + row;
    if (rowg < N) {
        const int rowB = Mout * 2;
        int segstart = (MT == 8) ? seg * 128 : seg * 48;
        int nch = (MT == 8) ? 8 : (seg ? 2 : 3);
        float hs[H], hd[H];
#pragma unroll
        for (int h = 0; h < H; h++) { hs[h] = 0.f; hd[h] = 0.f; }
        for (int i = 0; i < nch; i++) {
            int cb = segstart + i * 16;
            f16x8 v = *reinterpret_cast<const f16x8*>(
                &ldsb[row * HST + (cb ^ ((row & 7) << 4))]);
            *reinterpret_cast<f16x8*>((char*)Hout + (size_t)rowg * rowB + cb) = v;
            int hh = (H == 1) ? 0 : (cb >> 6);
            int colb = cb >> 1;
            float ps = 0.f, pd = 0.f;
#pragma unroll
            for (int j = 0; j < 8; j++) {
                float f = (float)v[j];
                ps = fmaf(f, a_src[colb + j], ps);
                pd = fmaf(f, a_dst[colb + j], pd);
            }
            hs[hh] += ps; hd[hh] += pd;
        }
        if (H == 4) {
#pragma unroll
            for (int t = 0; t < 2; t++) {
                int hh = 2 * seg + t;
                als[rowg * 4 + hh] = hs[hh];
                ald[rowg * 4 + hh] = hd[hh];
                atomicMax(&lmax[hh], f2oi(hs[hh]));
                atomicMax(&lmax[4 + hh], f2oi(hd[hh]));
            }
        } else {
            float s = hs[0] + __shfl_xor(hs[0], 1, 64);
            float d = hd[0] + __shfl_xor(hd[0], 1, 64);
            if (seg == 0) {
                als[rowg] = s; ald[rowg] = d;
                atomicMax(&lmax[0], f2oi(s));
                atomicMax(&lmax[4], f2oi(d));
            }
        }
    }
    __syncthreads();
    if (tid < H) atomicMax(&mint[tid], lmax[tid]);
    if (tid >= 8 && tid < 8 + H) atomicMax(&mint[4 + tid - 8], lmax[4 + tid - 8]);
}

// ---------- atomic-free CSR build (two-level counting sort) ----------
__global__ __launch_bounds__(256) void p1_hist(const int* __restrict__ src,
                                               const int* __restrict__ dst,
                                               int E_real, int E_tot, int NB, int NBLK,
                                               int EPB, int* __restrict__ cntmat) {
    __shared__ int hist[1024];
    for (int i = threadIdx.x; i < NB; i += 256) hist[i] = 0;
    __syncthreads();
    int e0 = blockIdx.x * EPB;
    int e1 = min(e0 + EPB, E_tot);
    for (int e = e0 + threadIdx.x; e < e1; e += 256) {
        int d = (e < E_real) ? dst[e] : e - E_real;
        atomicAdd(&hist[d >> 6], 1);
    }
    __syncthreads();
    for (int b = threadIdx.x; b < NB; b += 256)
        cntmat[b * NBLK + blockIdx.x] = hist[b];
}

__global__ __launch_bounds__(256) void p_scancols(int* __restrict__ cntmat,
                                                  int* __restrict__ colTot, int NBLK) {
    __shared__ int sh[256];
    int b = blockIdx.x;
    int t = threadIdx.x;
    if (t < NBLK) sh[t] = cntmat[b * NBLK + t];
    __syncthreads();
    if (t == 0) {
        int run = 0;
        for (int i = 0; i < NBLK; i++) { int v = sh[i]; sh[i] = run; run += v; }
        colTot[b] = run;
    }
    __syncthreads();
    if (t < NBLK) cntmat[b * NBLK + t] = sh[t];
}

__global__ __launch_bounds__(256) void p_scancoarse(const int* __restrict__ colTot,
                                                    int* __restrict__ coarseOff,
                                                    int* __restrict__ offsets,
                                                    int NB, int N, int E_tot) {
    __shared__ int sh[256];
    int t = threadIdx.x, base = t * 4;
    int v0 = 0, v1 = 0, v2 = 0, v3 = 0;
    if (base + 0 < NB) v0 = colTot[base + 0];
    if (base + 1 < NB) v1 = colTot[base + 1];
    if (base + 2 < NB) v2 = colTot[base + 2];
    if (base + 3 < NB) v3 = colTot[base + 3];
    int s = v0 + v1 + v2 + v3;
    sh[t] = s;
    __syncthreads();
    for (int off = 1; off < 256; off <<= 1) {
        int u = (t >= off) ? sh[t - off] : 0;
        __syncthreads();
        sh[t] += u;
        __syncthreads();
    }
    int run = sh[t] - s;
    if (base + 0 < NB) { coarseOff[base + 0] = run; run += v0; }
    if (base + 1 < NB) { coarseOff[base + 1] = run; run += v1; }
    if (base + 2 < NB) { coarseOff[base + 2] = run; run += v2; }
    if (base + 3 < NB) { coarseOff[base + 3] = run; }
    if (t == 255) { coarseOff[NB] = sh[255]; offsets[N] = E_tot; }
}

__global__ __launch_bounds__(256) void p2_scatter(const int* __restrict__ src,
                                                  const int* __restrict__ dst,
                                                  int E_real, int E_tot, int NB, int NBLK,
                                                  int EPB, const int* __restrict__ cntmat,
                                                  const int* __restrict__ coarseOff,
                                                  int2* __restrict__ pairs) {
    __shared__ int cur[1024];
    for (int b = threadIdx.x; b < NB; b += 256)
        cur[b] = coarseOff[b] + cntmat[b * NBLK + blockIdx.x];
    __syncthreads();
    int e0 = blockIdx.x * EPB;
    int e1 = min(e0 + EPB, E_tot);
    for (int e = e0 + threadIdx.x; e < e1; e += 256) {
        int s, d;
        if (e < E_real) { s = src[e]; d = dst[e]; } else { s = d = e - E_real; }
        int pos = atomicAdd(&cur[d >> 6], 1);
        pairs[pos] = make_int2(s, d);
    }
}

__global__ __launch_bounds__(256) void p3_bucket(const int2* __restrict__ pairs,
                                                 const int* __restrict__ coarseOff,
                                                 int NB, int N, int* __restrict__ offsets,
                                                 int* __restrict__ csr_src) {
    __shared__ int lh[64], lc[64];
    int b = blockIdx.x;
    int beg = coarseOff[b], end = coarseOff[b + 1];
    int t = threadIdx.x;
    if (t < 64) lh[t] = 0;
    __syncthreads();
    for (int i = beg + t; i < end; i += 256)
        atomicAdd(&lh[pairs[i].y & 63], 1);
    __syncthreads();
    if (t < 64) {
        int v = lh[t];
        int run = v;
#pragma unroll
        for (int off = 1; off < 64; off <<= 1) {
            int o = __shfl_up(run, off, 64);
            if (t >= off) run += o;
        }
        int ex = run - v;
        lc[t] = ex;
        int node = b * 64 + t;
        if (node < N) offsets[node] = beg + ex;
    }
    __syncthreads();
    for (int i = beg + t; i < end; i += 256) {
        int2 p = pairs[i];
        int pos = atomicAdd(&lc[p.y & 63], 1);
        csr_src[beg + pos] = p.x;
    }
}

// ---------- fused GAT aggregate, layers 0/1 (H=4,C=32), fp16 h ----------
__global__ __launch_bounds__(256) void gat_agg128(const int* __restrict__ offsets,
                                                  const int* __restrict__ csr_src,
                                                  const __half* __restrict__ h,
                                                  const float* __restrict__ als,
                                                  const float* __restrict__ ald,
                                                  const int* __restrict__ mint,
                                                  const float* __restrict__ bias,
                                                  float* __restrict__ out, int N) {
    __shared__ float wlds[4][64][4];
    __shared__ int   slds[4][64];
    int wid = threadIdx.x >> 6;
    int lane = threadIdx.x & 63;
    int gwid = (blockIdx.x * 256 + threadIdx.x) >> 6;
    int nWaves = (gridDim.x * 256) >> 6;
    int hh = lane >> 4;
    const __half2* h2 = (const __half2*)h;
    const float4* als4 = (const float4*)als;
    const float4* ald4 = (const float4*)ald;
    float2 bv = ((const float2*)bias)[lane];

    float4 shift;
    {
        float v;
        v = oi2f(mint[0]) + oi2f(mint[4]); shift.x = v > 0.f ? v : 0.2f * v;
        v = oi2f(mint[1]) + oi2f(mint[5]); shift.y = v > 0.f ? v : 0.2f * v;
        v = oi2f(mint[2]) + oi2f(mint[6]); shift.z = v > 0.f ? v : 0.2f * v;
        v = oi2f(mint[3]) + oi2f(mint[7]); shift.w = v > 0.f ? v : 0.2f * v;
    }

    for (int n = gwid; n < N; n += nWaves) {
        int beg = offsets[n], end = offsets[n + 1];
        float4 adn = ald4[n];
        float accx = 0.f, accy = 0.f, den = 0.f;

        for (int c0 = beg; c0 < end; c0 += 64) {
            int e = c0 + lane;
            if (e < end) {
                int s = csr_src[e];
                float4 a4 = als4[s];
                float4 w; float v;
                v = a4.x + adn.x; v = v > 0.f ? v : 0.2f * v; w.x = __expf(v - shift.x);
                v = a4.y + adn.y; v = v > 0.f ? v : 0.2f * v; w.y = __expf(v - shift.y);
                v = a4.z + adn.z; v = v > 0.f ? v : 0.2f * v; w.z = __expf(v - shift.z);
                v = a4.w + adn.w; v = v > 0.f ? v : 0.2f * v; w.w = __expf(v - shift.w);
                *reinterpret_cast<float4*>(&wlds[wid][lane][0]) = w;
                slds[wid][lane] = s;
            }
            int cnt = end - c0; if (cnt > 64) cnt = 64;
            int p = 0;
            for (; p + 4 <= cnt; p += 4) {
                float w0 = wlds[wid][p][hh];     int s0 = slds[wid][p];
                float w1 = wlds[wid][p + 1][hh]; int s1 = slds[wid][p + 1];
                float w2 = wlds[wid][p + 2][hh]; int s2 = slds[wid][p + 2];
                float w3 = wlds[wid][p + 3][hh]; int s3 = slds[wid][p + 3];
                float2 f0 = __half22float2(h2[(size_t)s0 * 64 + lane]);
                float2 f1 = __half22float2(h2[(size_t)s1 * 64 + lane]);
                float2 f2 = __half22float2(h2[(size_t)s2 * 64 + lane]);
                float2 f3 = __half22float2(h2[(size_t)s3 * 64 + lane]);
                den += (w0 + w1) + (w2 + w3);
                accx = fmaf(f0.x, w0, fmaf(f1.x, w1, fmaf(f2.x, w2, fmaf(f3.x, w3, accx))));
                accy = fmaf(f0.y, w0, fmaf(f1.y, w1, fmaf(f2.y, w2, fmaf(f3.y, w3, accy))));
            }
            for (; p < cnt; ++p) {
                float w0 = wlds[wid][p][hh]; int s0 = slds[wid][p];
                float2 f0 = __half22float2(h2[(size_t)s0 * 64 + lane]);
                den += w0;
                accx = fmaf(f0.x, w0, accx);
                accy = fmaf(f0.y, w0, accy);
            }
        }
        float inv = 1.f / den;
        float r0 = accx * inv + bv.x;
        float r1 = accy * inv + bv.y;
        float2 o;
        o.x = r0 > 0.f ? r0 : expm1f(r0);
        o.y = r1 > 0.f ? r1 : expm1f(r1);
        ((float2*)out)[(size_t)n * 64 + lane] = o;
    }
}

// ---------- fused GAT aggregate + log_softmax, layer 2 (H=1,C=40), fp16 h ----------
__global__ __launch_bounds__(256) void gat_agg40_lsm(const int* __restrict__ offsets,
                                                     const int* __restrict__ csr_src,
                                                     const __half* __restrict__ h,
                                                     const float* __restrict__ als,
                                                     const float* __restrict__ ald,
                                                     const int* __restrict__ mint,
                                                     const float* __restrict__ b2,
                                                     float* __restrict__ out, int N) {
    __shared__ float wlds[4][64];
    __shared__ int   slds[4][64];
    int wid = threadIdx.x >> 6;
    int lane = threadIdx.x & 63;
    int gwid = (blockIdx.x * 256 + threadIdx.x) >> 6;
    int nWaves = (gridDim.x * 256) >> 6;

    float shift;
    {
        float v = oi2f(mint[0]) + oi2f(mint[4]);
        shift = v > 0.f ? v : 0.2f * v;
    }

    for (int n = gwid; n < N; n += nWaves) {
        int beg = offsets[n], end = offsets[n + 1];
        float adn = ald[n];
        float acc = 0.f, den = 0.f;

        for (int c0 = beg; c0 < end; c0 += 64) {
            int e = c0 + lane;
            if (e < end) {
                int s = csr_src[e];
                float v = als[s] + adn; v = v > 0.f ? v : 0.2f * v;
                wlds[wid][lane] = __expf(v - shift);
                slds[wid][lane] = s;
            }
            int cnt = end - c0; if (cnt > 64) cnt = 64;
            int p = 0;
            for (; p + 4 <= cnt; p += 4) {
                float w0 = wlds[wid][p];     int s0 = slds[wid][p];
                float w1 = wlds[wid][p + 1]; int s1 = slds[wid][p + 1];
                float w2 = wlds[wid][p + 2]; int s2 = slds[wid][p + 2];
                float w3 = wlds[wid][p + 3]; int s3 = slds[wid][p + 3];
                float h0 = (lane < 40) ? __half2float(h[(size_t)s0 * 40 + lane]) : 0.f;
                float h1 = (lane < 40) ? __half2float(h[(size_t)s1 * 40 + lane]) : 0.f;
                float h2v = (lane < 40) ? __half2float(h[(size_t)s2 * 40 + lane]) : 0.f;
                float h3 = (lane < 40) ? __half2float(h[(size_t)s3 * 40 + lane]) : 0.f;
                den += (w0 + w1) + (w2 + w3);
                acc = fmaf(h0, w0, fmaf(h1, w1, fmaf(h2v, w2, fmaf(h3, w3, acc))));
            }
            for (; p < cnt; ++p) {
                float w0 = wlds[wid][p]; int s0 = slds[wid][p];
                float h0 = (lane < 40) ? __half2float(h[(size_t)s0 * 40 + lane]) : 0.f;
                den += w0;
                acc = fmaf(h0, w0, acc);
            }
        }
        float val = (lane < 40) ? acc / den + b2[lane] : -INFINITY;
        float mx = val;
#pragma unroll
        for (int off = 32; off >= 1; off >>= 1) mx = fmaxf(mx, __shfl_xor(mx, off, 64));
        float pe = (lane < 40) ? __expf(val - mx) : 0.f;
        float sum = pe;
#pragma unroll
        for (int off = 32; off >= 1; off >>= 1) sum += __shfl_xor(sum, off, 64);
        if (lane < 40) out[n * 40 + lane] = val - mx - logf(sum);
    }
}

extern "C" void kernel_launch(void* const* d_in, const int* in_sizes, int n_in,
                              void* d_out, int out_size, void* d_ws, size_t ws_size,
                              hipStream_t stream) {
    const float* x      = (const float*)d_in[0];
    const int*   ei     = (const int*)d_in[1];
    const float* W0     = (const float*)d_in[2];
    const float* a_src0 = (const float*)d_in[3];
    const float* a_dst0 = (const float*)d_in[4];
    const float* b0     = (const float*)d_in[5];
    const float* W1     = (const float*)d_in[6];
    const float* a_src1 = (const float*)d_in[7];
    const float* a_dst1 = (const float*)d_in[8];
    const float* b1     = (const float*)d_in[9];
    const float* W2     = (const float*)d_in[10];
    const float* a_src2 = (const float*)d_in[11];
    const float* a_dst2 = (const float*)d_in[12];
    const float* b2     = (const float*)d_in[13];

    const int N = in_sizes[0] / 128;          // 50000
    const int E_real = in_sizes[1] / 2;       // 800000
    const int E_tot = E_real + N;
    const int* src = ei;
    const int* dst = ei + E_real;

    const int EPB  = 4096;
    const int NBLK = (E_tot + EPB - 1) / EPB; // 208
    const int NB   = (N + 63) >> 6;           // 782

    unsigned char* ws = (unsigned char*)d_ws;
    const size_t szH16 = (size_t)N * 128 * sizeof(__half);
    const size_t szAcc = (size_t)N * 128 * sizeof(float);
    size_t off = 0;
    __half* bufH    = (__half*)(ws + off); off += szH16;
    float*  bufAcc  = (float*)(ws + off);  off += szAcc;
    int2*   pairs   = (int2*)(ws + off);   off += (size_t)E_tot * sizeof(int2);
    int*    csr_src = (int*)(ws + off);    off += (size_t)E_tot * sizeof(int);
    float*  als     = (float*)(ws + off);  off += (size_t)N * 4 * sizeof(float);
    float*  ald     = (float*)(ws + off);  off += (size_t)N * 4 * sizeof(float);
    int*    cntmat  = (int*)(ws + off);    off += (size_t)NB * NBLK * sizeof(int);
    int*    colTot  = (int*)(ws + off);    off += (size_t)NB * sizeof(int);
    int*    coarseOff = (int*)(ws + off);  off += (size_t)(NB + 1) * sizeof(int);
    int*    offsets = (int*)(ws + off);    off += (size_t)(N + 1) * sizeof(int);
    int*    mint    = (int*)(ws + off);    off += 24 * sizeof(int);

    const int B = 256;
    const int gRows128 = (N + 127) / 128;     // 391
    const int gAgg  = 2048;

    // ===== CSR build (atomic-free) =====
    hipMemsetAsync(mint, 0x80, 24 * sizeof(int), stream);
    p1_hist<<<NBLK, B, 0, stream>>>(src, dst, E_real, E_tot, NB, NBLK, EPB, cntmat);
    p_scancols<<<NB, B, 0, stream>>>(cntmat, colTot, NBLK);
    p_scancoarse<<<1, B, 0, stream>>>(colTot, coarseOff, offsets, NB, N, E_tot);
    p2_scatter<<<NBLK, B, 0, stream>>>(src, dst, E_real, E_tot, NB, NBLK, EPB, cntmat, coarseOff, pairs);
    p3_bucket<<<NB, B, 0, stream>>>(pairs, coarseOff, NB, N, offsets, csr_src);

    // ===== Layer 0 =====
    gemm_mfma<8, 4><<<gRows128, B, 0, stream>>>(x, W0, a_src0, a_dst0, bufH, 128, als, ald, mint, N);
    gat_agg128<<<gAgg, B, 0, stream>>>(offsets, csr_src, bufH, als, ald, mint, b0, bufAcc, N);

    // ===== Layer 1 =====
    gemm_mfma<8, 4><<<gRows128, B, 0, stream>>>(bufAcc, W1, a_src1, a_dst1, bufH, 128, als, ald, mint + 8, N);
    gat_agg128<<<gAgg, B, 0, stream>>>(offsets, csr_src, bufH, als, ald, mint + 8, b1, bufAcc, N);

    // ===== Layer 2 =====
    gemm_mfma<3, 1><<<gRows128, B, 0, stream>>>(bufAcc, W2, a_src2, a_dst2, bufH, 40, als, ald, mint + 16, N);
    gat_agg40_lsm<<<gAgg, B, 0, stream>>>(offsets, csr_src, bufH, als, ald, mint + 16, b2,
                                          (float*)d_out, N);
}